// Round 10
// baseline (597.901 us; speedup 1.0000x reference)
//
#include <hip/hip_runtime.h>

// Problem constants
#define B_ 32
#define N_ 8192
#define D_ 128
#define H_ 128
#define R_ (B_ * N_)   // 262144 rows total

#define NBLK 512       // 512 blocks x 8 waves = 4096 waves; 4 tasks (16 rows) each

typedef _Float16 f16;
typedef __attribute__((ext_vector_type(4))) _Float16 f16x4;
typedef __attribute__((ext_vector_type(8))) _Float16 f16x8;
typedef __attribute__((ext_vector_type(4))) float f32x4;

// Workspace layout (bytes)
static constexpr size_t WPACK_OFF = 0;                       // 2*128*128 f16 = 64 KiB
static constexpr size_t VPART_OFF = 65536;                   // 4096*128 f32 = 2 MiB
static constexpr size_t SPART_OFF = VPART_OFF + 4096ull * 128 * 4;  // 4096 f32

__device__ __forceinline__ float silu_f(float v) {
    return v * __builtin_amdgcn_rcpf(1.0f + __expf(-v));
}

__device__ __forceinline__ f32x4 mfma16(f16x8 a, f16x8 b, f32x4 c) {
    return __builtin_amdgcn_mfma_f32_16x16x32_f16(a, b, c, 0, 0, 0);
}

// ---------------------------------------------------------------------------
// K0: prepack Wg1, Wn1 (fp32 row-major [k][n] 128x128) into fp16 MFMA
// fragment order: frag[(nt*4+kc)*64 + lane][j]
//   = W[(kc*32 + (lane>>4)*8 + j)][nt*16 + (lane&15)]
// ---------------------------------------------------------------------------
__global__ void k0_prepack(const float* __restrict__ Wg1,
                           const float* __restrict__ Wn1,
                           f16* __restrict__ wp) {
    int tid = blockIdx.x * 256 + threadIdx.x;  // 0..32767
    int m    = tid >> 14;
    int r    = tid & 16383;
    int j    = r & 7;
    int lane = (r >> 3) & 63;
    int kc   = (r >> 9) & 3;
    int nt   = r >> 11;
    int k = kc * 32 + (lane >> 4) * 8 + j;
    int n = nt * 16 + (lane & 15);
    const float* W = m ? Wn1 : Wg1;
    wp[tid] = (f16)W[k * 128 + n];
}

// ---------------------------------------------------------------------------
// K1: BARRIER-FREE main loop (the r0-r9 plateau at 56-79 µs vs the 21 µs BW
// floor was the block-wide load->barrier->consume cycle; per-wave stalls
// couldn't be hidden by TLP).
// Row partition: wave wgid owns rows [wgid*64, wgid*64+64) as 4 tasks of 16
// rows x all 128 cols. Gate score = full 128-col sum -> completes WITHIN the
// wave (shfl over q). No gpart, no x LDS, no main-loop barriers; 16
// independent waves/CU hide HBM latency via TLP.
// x frags load DIRECT from global (each element read once chip-wide; rows
// are partitioned). Weights in LDS (64 KiB, staged once, single barrier),
// conflict-free ds_read_b128 per MFMA. Biases fold into MFMA C-init.
// Lane (q,c): a[kc][j] = x[row0+c][kc*32+q*8+j]; D[col=st*16+q*4+r][row=c].
// V[8][4] accumulates e*h over all 64 rows in regs; one c-lane shfl-reduce
// + one vpart/spart write per wave at the end.
// n2 stays hoisted (applied post-pooling in K2; softmax weights sum to 1).
// ---------------------------------------------------------------------------
__global__ __launch_bounds__(512, 4) void k1_fused(
        const float* __restrict__ x,
        const float* __restrict__ bg1, const float* __restrict__ wg2,
        const float* __restrict__ bg2, const float* __restrict__ bn1,
        const f16* __restrict__ wp,
        float* __restrict__ vpart, float* __restrict__ spart) {
    __shared__ f16 wlds[2 * 128 * 128];   // 64 KiB: fg1 frags then fn1 frags
    __shared__ float blds[3 * 128];       // bg1 | bn1 | wg2

    const int tid  = threadIdx.x;      // 0..511
    const int w    = tid >> 6;
    const int lane = tid & 63;
    const int q    = lane >> 4;
    const int c    = lane & 15;

    // ---- stage weights + biases to LDS (once; the only barrier) ----
    const float4* wp4 = (const float4*)wp;   // 4096 x 16B
    float4* wl4 = (float4*)wlds;
#pragma unroll
    for (int i = 0; i < 8; ++i) wl4[i * 512 + tid] = wp4[i * 512 + tid];
    if (tid < 128) {
        blds[tid]       = bg1[tid];
        blds[128 + tid] = bn1[tid];
        blds[256 + tid] = wg2[tid];
    }
    const float bg2v = bg2[0];
    __syncthreads();

    const int wgid = blockIdx.x * 8 + w;     // 0..4095; batch = wgid/128
    const f16x8* wv = (const f16x8*)wlds;    // frag (st*4+kc)*64 + lane

    float V[8][4] = {{0.f,0.f,0.f,0.f},{0.f,0.f,0.f,0.f},{0.f,0.f,0.f,0.f},
                     {0.f,0.f,0.f,0.f},{0.f,0.f,0.f,0.f},{0.f,0.f,0.f,0.f},
                     {0.f,0.f,0.f,0.f},{0.f,0.f,0.f,0.f}};
    float Sacc = 0.f;

#pragma unroll 1
    for (int task = 0; task < 4; ++task) {
        // ---- direct global frag loads: 8 float4 (32B x 4 kc) per lane ----
        const long row0 = (long)wgid * 64 + task * 16 + c;
        const float4* xr = (const float4*)(x + row0 * 128);
        float4 xv[8];
#pragma unroll
        for (int kc = 0; kc < 4; ++kc) {
            xv[kc * 2]     = xr[kc * 8 + q * 2];
            xv[kc * 2 + 1] = xr[kc * 8 + q * 2 + 1];
        }
        f16x8 a[4];
#pragma unroll
        for (int kc = 0; kc < 4; ++kc) {
            float4 f0 = xv[kc * 2], f1 = xv[kc * 2 + 1];
            f16x8 av = {(f16)f0.x, (f16)f0.y, (f16)f0.z, (f16)f0.w,
                        (f16)f1.x, (f16)f1.y, (f16)f1.z, (f16)f1.w};
            a[kc] = av;
        }

        // ---- all 8 col-stripes: gate1 + n1 (bias via MFMA C-init) ----
        float p = 0.f;
        f16x4 h[8];
#pragma unroll
        for (int st = 0; st < 8; ++st) {
            float4 bgi = *(const float4*)&blds[st * 16 + q * 4];
            float4 bni = *(const float4*)&blds[128 + st * 16 + q * 4];
            float4 wgi = *(const float4*)&blds[256 + st * 16 + q * 4];
            f32x4 ag = {bgi.x, bgi.y, bgi.z, bgi.w};
            f32x4 an = {bni.x, bni.y, bni.z, bni.w};
#pragma unroll
            for (int kc = 0; kc < 4; ++kc) {
                ag = mfma16(wv[(st * 4 + kc) * 64 + lane], a[kc], ag);
                an = mfma16(wv[2048 + (st * 4 + kc) * 64 + lane], a[kc], an);
            }
            f16x4 h4;
#pragma unroll
            for (int r = 0; r < 4; ++r) h4[r] = (f16)silu_f(an[r]);
            h[st] = h4;
            p += silu_f(ag[0]) * wgi.x + silu_f(ag[1]) * wgi.y
               + silu_f(ag[2]) * wgi.z + silu_f(ag[3]) * wgi.w;
        }
        // full 128-col gate sum: reduce over q within the wave
        p += __shfl_xor(p, 16);
        p += __shfl_xor(p, 32);
        float e4 = __expf(p + bg2v);
        Sacc += e4;
#pragma unroll
        for (int st = 0; st < 8; ++st)
#pragma unroll
            for (int r = 0; r < 4; ++r)
                V[st][r] += e4 * (float)h[st][r];
    }

    // ---- once per wave: reduce V over the 16 c-lanes; write partials ----
#pragma unroll
    for (int m = 1; m < 16; m <<= 1)
#pragma unroll
        for (int st = 0; st < 8; ++st)
#pragma unroll
            for (int r = 0; r < 4; ++r) V[st][r] += __shfl_xor(V[st][r], m);
    if (c == 0) {
#pragma unroll
        for (int st = 0; st < 8; ++st) {
            float4 o = {V[st][0], V[st][1], V[st][2], V[st][3]};
            *(float4*)&vpart[(long)wgid * 128 + st * 16 + q * 4] = o;
        }
    }
#pragma unroll
    for (int m = 1; m < 16; m <<= 1) Sacc += __shfl_xor(Sacc, m);
    if (lane == 0) spart[wgid] = Sacc;
}

// ---------------------------------------------------------------------------
// K2: combine per-wave partials, then apply the pooled n2 linear layer:
//   out[b] = (sum_k vpart[b,k] / S_b) @ Wn2 + bn2      (Sigma attn = 1)
// 32 blocks (one per batch) x 256 threads. 128 partials per batch.
// ---------------------------------------------------------------------------
__global__ void k2_combine(const float* __restrict__ vpart,
                           const float* __restrict__ spart,
                           const float* __restrict__ Wn2,
                           const float* __restrict__ bn2,
                           float* __restrict__ out) {
    const int b = blockIdx.x;
    const int t = threadIdx.x;   // 0..255

    __shared__ float pooled[128];
    __shared__ float sred2[2];

    // V partial sum: threads 0..127 each own one output column
    float v = 0.f;
    if (t < 128) {
        const float* vp = vpart + (long)b * 128 * 128;
#pragma unroll 8
        for (int k = 0; k < 128; ++k) v += vp[k * 128 + t];
    }

    // Denominator: threads 0..127 hold one spart each; full-wave shuffles.
    float s = (t < 128) ? spart[b * 128 + t] : 0.f;
#pragma unroll
    for (int m = 1; m < 64; m <<= 1) s += __shfl_xor(s, m);
    if (t < 128 && (t & 63) == 0) sred2[t >> 6] = s;
    __syncthreads();

    if (t < 128) pooled[t] = v / (sred2[0] + sred2[1]);
    __syncthreads();
    if (t < 128) {
        float acc = bn2[t];
#pragma unroll 8
        for (int k = 0; k < 128; ++k) acc += pooled[k] * Wn2[k * 128 + t];
        out[b * 128 + t] = acc;
    }
}

// ---------------------------------------------------------------------------
extern "C" void kernel_launch(void* const* d_in, const int* in_sizes, int n_in,
                              void* d_out, int out_size, void* d_ws, size_t ws_size,
                              hipStream_t stream) {
    const float* x   = (const float*)d_in[0];
    const float* Wg1 = (const float*)d_in[1];
    const float* bg1 = (const float*)d_in[2];
    const float* Wg2 = (const float*)d_in[3];
    const float* bg2 = (const float*)d_in[4];
    const float* Wn1 = (const float*)d_in[5];
    const float* bn1 = (const float*)d_in[6];
    const float* Wn2 = (const float*)d_in[7];
    const float* bn2 = (const float*)d_in[8];
    float* out = (float*)d_out;

    char* ws = (char*)d_ws;
    f16*   wp    = (f16*)(ws + WPACK_OFF);
    float* vpart = (float*)(ws + VPART_OFF);
    float* spart = (float*)(ws + SPART_OFF);

    k0_prepack<<<128, 256, 0, stream>>>(Wg1, Wn1, wp);
    k1_fused<<<NBLK, 512, 0, stream>>>(x, bg1, Wg2, bg2, bn1, wp, vpart, spart);
    k2_combine<<<32, 256, 0, stream>>>(vpart, spart, Wn2, bn2, out);
}

// Round 11
// 595.658 us; speedup vs baseline: 1.0038x; 1.0038x over previous
//
#include <hip/hip_runtime.h>

// Problem constants
#define B_ 32
#define N_ 8192
#define D_ 128
#define H_ 128
#define R_ (B_ * N_)   // 262144 rows total

#define NBLK 512       // 512 blocks x 8 waves = 4096 waves; 4 tasks (16 rows) each

typedef _Float16 f16;
typedef __attribute__((ext_vector_type(4))) _Float16 f16x4;
typedef __attribute__((ext_vector_type(8))) _Float16 f16x8;
typedef __attribute__((ext_vector_type(4))) float f32x4;

// Workspace layout (bytes)
static constexpr size_t WPACK_OFF = 0;                       // 2*128*128 f16 = 64 KiB
static constexpr size_t VPART_OFF = 65536;                   // 4096*128 f32 = 2 MiB
static constexpr size_t SPART_OFF = VPART_OFF + 4096ull * 128 * 4;  // 4096 f32

__device__ __forceinline__ float silu_f(float v) {
    return v * __builtin_amdgcn_rcpf(1.0f + __expf(-v));
}

__device__ __forceinline__ f32x4 mfma16(f16x8 a, f16x8 b, f32x4 c) {
    return __builtin_amdgcn_mfma_f32_16x16x32_f16(a, b, c, 0, 0, 0);
}

// ---------------------------------------------------------------------------
// K0: prepack Wg1, Wn1 (fp32 row-major [k][n] 128x128) into fp16 MFMA
// fragment order: frag[(nt*4+kc)*64 + lane][j]
//   = W[(kc*32 + (lane>>4)*8 + j)][nt*16 + (lane&15)]
// ---------------------------------------------------------------------------
__global__ void k0_prepack(const float* __restrict__ Wg1,
                           const float* __restrict__ Wn1,
                           f16* __restrict__ wp) {
    int tid = blockIdx.x * 256 + threadIdx.x;  // 0..32767
    int m    = tid >> 14;
    int r    = tid & 16383;
    int j    = r & 7;
    int lane = (r >> 3) & 63;
    int kc   = (r >> 9) & 3;
    int nt   = r >> 11;
    int k = kc * 32 + (lane >> 4) * 8 + j;
    int n = nt * 16 + (lane & 15);
    const float* W = m ? Wn1 : Wg1;
    wp[tid] = (f16)W[k * 128 + n];
}

// ---------------------------------------------------------------------------
// K1: r10's barrier-free row-partitioned structure, with the occupancy
// PINNED: amdgpu_waves_per_eu(4,4) forces exactly 4 waves/EU -> firm
// 128-VGPR budget. r10's failure was the allocator voluntarily targeting
// 8 waves/EU (VGPR_Count=64) for this barrier-free kernel and spilling the
// ~93-reg live set (WRITE_SIZE 360 MB of scratch). Zero dataflow change.
// Row partition: wave wgid owns rows [wgid*64, wgid*64+64) as 4 tasks of 16
// rows x all 128 cols. Gate score = full 128-col sum -> completes WITHIN the
// wave (shfl over q). No gpart, no x LDS, no main-loop barriers; 16
// independent waves/CU hide HBM latency via TLP.
// x frags load DIRECT from global (each element read once chip-wide; rows
// are partitioned; 64B segments fully consumed). Weights in LDS (64 KiB,
// staged once, single barrier), conflict-free ds_read_b128 per MFMA.
// Biases fold into MFMA C-init.
// Lane (q,c): a[kc][j] = x[row0+c][kc*32+q*8+j]; D[col=st*16+q*4+r][row=c].
// V[8][4] accumulates e*h over all 64 rows in regs; one c-lane shfl-reduce
// + one vpart/spart write per wave at the end.
// n2 stays hoisted (applied post-pooling in K2; softmax weights sum to 1).
// ---------------------------------------------------------------------------
__global__ __launch_bounds__(512)
__attribute__((amdgpu_waves_per_eu(4, 4)))
void k1_fused(
        const float* __restrict__ x,
        const float* __restrict__ bg1, const float* __restrict__ wg2,
        const float* __restrict__ bg2, const float* __restrict__ bn1,
        const f16* __restrict__ wp,
        float* __restrict__ vpart, float* __restrict__ spart) {
    __shared__ f16 wlds[2 * 128 * 128];   // 64 KiB: fg1 frags then fn1 frags
    __shared__ float blds[3 * 128];       // bg1 | bn1 | wg2

    const int tid  = threadIdx.x;      // 0..511
    const int w    = tid >> 6;
    const int lane = tid & 63;
    const int q    = lane >> 4;
    const int c    = lane & 15;

    // ---- stage weights + biases to LDS (once; the only barrier) ----
    const float4* wp4 = (const float4*)wp;   // 4096 x 16B
    float4* wl4 = (float4*)wlds;
#pragma unroll
    for (int i = 0; i < 8; ++i) wl4[i * 512 + tid] = wp4[i * 512 + tid];
    if (tid < 128) {
        blds[tid]       = bg1[tid];
        blds[128 + tid] = bn1[tid];
        blds[256 + tid] = wg2[tid];
    }
    const float bg2v = bg2[0];
    __syncthreads();

    const int wgid = blockIdx.x * 8 + w;     // 0..4095; batch = wgid/128
    const f16x8* wv = (const f16x8*)wlds;    // frag (st*4+kc)*64 + lane

    float V[8][4] = {{0.f,0.f,0.f,0.f},{0.f,0.f,0.f,0.f},{0.f,0.f,0.f,0.f},
                     {0.f,0.f,0.f,0.f},{0.f,0.f,0.f,0.f},{0.f,0.f,0.f,0.f},
                     {0.f,0.f,0.f,0.f},{0.f,0.f,0.f,0.f}};
    float Sacc = 0.f;

#pragma unroll 1
    for (int task = 0; task < 4; ++task) {
        // ---- direct global frag loads: 8 float4 (32B x 4 kc) per lane ----
        const long row0 = (long)wgid * 64 + task * 16 + c;
        const float4* xr = (const float4*)(x + row0 * 128);
        float4 xv[8];
#pragma unroll
        for (int kc = 0; kc < 4; ++kc) {
            xv[kc * 2]     = xr[kc * 8 + q * 2];
            xv[kc * 2 + 1] = xr[kc * 8 + q * 2 + 1];
        }
        f16x8 a[4];
#pragma unroll
        for (int kc = 0; kc < 4; ++kc) {
            float4 f0 = xv[kc * 2], f1 = xv[kc * 2 + 1];
            f16x8 av = {(f16)f0.x, (f16)f0.y, (f16)f0.z, (f16)f0.w,
                        (f16)f1.x, (f16)f1.y, (f16)f1.z, (f16)f1.w};
            a[kc] = av;
        }

        // ---- all 8 col-stripes: gate1 + n1 (bias via MFMA C-init) ----
        float p = 0.f;
        f16x4 h[8];
#pragma unroll
        for (int st = 0; st < 8; ++st) {
            float4 bgi = *(const float4*)&blds[st * 16 + q * 4];
            float4 bni = *(const float4*)&blds[128 + st * 16 + q * 4];
            float4 wgi = *(const float4*)&blds[256 + st * 16 + q * 4];
            f32x4 ag = {bgi.x, bgi.y, bgi.z, bgi.w};
            f32x4 an = {bni.x, bni.y, bni.z, bni.w};
#pragma unroll
            for (int kc = 0; kc < 4; ++kc) {
                ag = mfma16(wv[(st * 4 + kc) * 64 + lane], a[kc], ag);
                an = mfma16(wv[2048 + (st * 4 + kc) * 64 + lane], a[kc], an);
            }
            f16x4 h4;
#pragma unroll
            for (int r = 0; r < 4; ++r) h4[r] = (f16)silu_f(an[r]);
            h[st] = h4;
            p += silu_f(ag[0]) * wgi.x + silu_f(ag[1]) * wgi.y
               + silu_f(ag[2]) * wgi.z + silu_f(ag[3]) * wgi.w;
        }
        // full 128-col gate sum: reduce over q within the wave
        p += __shfl_xor(p, 16);
        p += __shfl_xor(p, 32);
        float e4 = __expf(p + bg2v);
        Sacc += e4;
#pragma unroll
        for (int st = 0; st < 8; ++st)
#pragma unroll
            for (int r = 0; r < 4; ++r)
                V[st][r] += e4 * (float)h[st][r];
    }

    // ---- once per wave: reduce V over the 16 c-lanes; write partials ----
#pragma unroll
    for (int m = 1; m < 16; m <<= 1)
#pragma unroll
        for (int st = 0; st < 8; ++st)
#pragma unroll
            for (int r = 0; r < 4; ++r) V[st][r] += __shfl_xor(V[st][r], m);
    if (c == 0) {
#pragma unroll
        for (int st = 0; st < 8; ++st) {
            float4 o = {V[st][0], V[st][1], V[st][2], V[st][3]};
            *(float4*)&vpart[(long)wgid * 128 + st * 16 + q * 4] = o;
        }
    }
#pragma unroll
    for (int m = 1; m < 16; m <<= 1) Sacc += __shfl_xor(Sacc, m);
    if (lane == 0) spart[wgid] = Sacc;
}

// ---------------------------------------------------------------------------
// K2: combine per-wave partials, then apply the pooled n2 linear layer:
//   out[b] = (sum_k vpart[b,k] / S_b) @ Wn2 + bn2      (Sigma attn = 1)
// 32 blocks (one per batch) x 256 threads. 128 partials per batch.
// ---------------------------------------------------------------------------
__global__ void k2_combine(const float* __restrict__ vpart,
                           const float* __restrict__ spart,
                           const float* __restrict__ Wn2,
                           const float* __restrict__ bn2,
                           float* __restrict__ out) {
    const int b = blockIdx.x;
    const int t = threadIdx.x;   // 0..255

    __shared__ float pooled[128];
    __shared__ float sred2[2];

    // V partial sum: threads 0..127 each own one output column
    float v = 0.f;
    if (t < 128) {
        const float* vp = vpart + (long)b * 128 * 128;
#pragma unroll 8
        for (int k = 0; k < 128; ++k) v += vp[k * 128 + t];
    }

    // Denominator: threads 0..127 hold one spart each; full-wave shuffles.
    float s = (t < 128) ? spart[b * 128 + t] : 0.f;
#pragma unroll
    for (int m = 1; m < 64; m <<= 1) s += __shfl_xor(s, m);
    if (t < 128 && (t & 63) == 0) sred2[t >> 6] = s;
    __syncthreads();

    if (t < 128) pooled[t] = v / (sred2[0] + sred2[1]);
    __syncthreads();
    if (t < 128) {
        float acc = bn2[t];
#pragma unroll 8
        for (int k = 0; k < 128; ++k) acc += pooled[k] * Wn2[k * 128 + t];
        out[b * 128 + t] = acc;
    }
}

// ---------------------------------------------------------------------------
extern "C" void kernel_launch(void* const* d_in, const int* in_sizes, int n_in,
                              void* d_out, int out_size, void* d_ws, size_t ws_size,
                              hipStream_t stream) {
    const float* x   = (const float*)d_in[0];
    const float* Wg1 = (const float*)d_in[1];
    const float* bg1 = (const float*)d_in[2];
    const float* Wg2 = (const float*)d_in[3];
    const float* bg2 = (const float*)d_in[4];
    const float* Wn1 = (const float*)d_in[5];
    const float* bn1 = (const float*)d_in[6];
    const float* Wn2 = (const float*)d_in[7];
    const float* bn2 = (const float*)d_in[8];
    float* out = (float*)d_out;

    char* ws = (char*)d_ws;
    f16*   wp    = (f16*)(ws + WPACK_OFF);
    float* vpart = (float*)(ws + VPART_OFF);
    float* spart = (float*)(ws + SPART_OFF);

    k0_prepack<<<128, 256, 0, stream>>>(Wg1, Wn1, wp);
    k1_fused<<<NBLK, 512, 0, stream>>>(x, bg1, Wg2, bg2, bn1, wp, vpart, spart);
    k2_combine<<<32, 256, 0, stream>>>(vpart, spart, Wn2, bn2, out);
}